// Round 11
// baseline (328.772 us; speedup 1.0000x reference)
//
#include <hip/hip_runtime.h>
#include <hip/hip_fp16.h>
#include <math.h>

#define N_NODES 102400
#define N_EDGES 1638400
#define NB 100            // coarse buckets: node range 1024 (102400/1024)
#define PB 512            // partition blocks (512: 2 blocks/CU for latency-bound partC)
#define EPB (N_EDGES/PB)  // 3200 edges per partition block

union H4 { int2 i2; __half h[4]; };

typedef _Float16 f16;
typedef __attribute__((ext_vector_type(8))) _Float16 f16x8;
typedef __attribute__((ext_vector_type(4))) float f32x4;

// ---- fused pass A:
//   blocks 0..PB-1 : coarse dst/src histograms (LDS atomics)
//   blocks PB..    : layer-0 transform via MFMA (fp32->fp16 in-reg convert, fp32 accum)
__global__ __launch_bounds__(256) void fusedA_kernel(
    const int* __restrict__ src, const int* __restrict__ dst,
    int* __restrict__ histD, int* __restrict__ histS,
    const float* __restrict__ h, const float* __restrict__ W, __half* __restrict__ out) {
    const int tid = threadIdx.x;

    if (blockIdx.x < PB) {
        // ---------------- histogram role ----------------
        __shared__ int hD[NB], hS[NB];
        if (tid < NB) { hD[tid] = 0; hS[tid] = 0; }
        __syncthreads();
        int base = blockIdx.x * EPB;
        for (int i = tid; i < EPB; i += 256) {
            atomicAdd(&hD[dst[base + i] >> 10], 1);   // LDS atomic (CU-local)
            atomicAdd(&hS[src[base + i] >> 10], 1);
        }
        __syncthreads();
        if (tid < NB) {
            histD[blockIdx.x * NB + tid] = hD[tid];
            histS[blockIdx.x * NB + tid] = hS[tid];
        }
        return;
    }

    // ---------------- MFMA gemm role: out(fp16)[N][64] = h[N][128] @ W[128][64] ----------------
    const int lane = tid & 63;
    const int wid = tid >> 6;
    const int lr = lane & 15;        // A row / B col / D col (within 16x16 tile)
    const int kg = lane >> 4;        // k-group (0..3)
    const long bbase = (long)(blockIdx.x - PB) * 256 + wid * 16;

    f16x8 bf[4][4];
    #pragma unroll
    for (int ks = 0; ks < 4; ++ks)
        #pragma unroll
        for (int ct = 0; ct < 4; ++ct)
            #pragma unroll
            for (int j = 0; j < 8; ++j)
                bf[ks][ct][j] = (f16)W[(ks * 32 + kg * 8 + j) * 64 + ct * 16 + lr];

    #pragma unroll
    for (int t = 0; t < 4; ++t) {
        const long rowbase = bbase + t * 64;
        const float* hrow = h + (rowbase + lr) * 128 + kg * 8;
        f32x4 acc[4] = {{0,0,0,0},{0,0,0,0},{0,0,0,0},{0,0,0,0}};
        #pragma unroll
        for (int ks = 0; ks < 4; ++ks) {
            const float4 a0 = *(const float4*)(hrow + ks * 32);
            const float4 a1 = *(const float4*)(hrow + ks * 32 + 4);
            f16x8 af;
            af[0] = (f16)a0.x; af[1] = (f16)a0.y; af[2] = (f16)a0.z; af[3] = (f16)a0.w;
            af[4] = (f16)a1.x; af[5] = (f16)a1.y; af[6] = (f16)a1.z; af[7] = (f16)a1.w;
            #pragma unroll
            for (int ct = 0; ct < 4; ++ct)
                acc[ct] = __builtin_amdgcn_mfma_f32_16x16x32_f16(af, bf[ks][ct], acc[ct], 0, 0, 0);
        }
        #pragma unroll
        for (int ct = 0; ct < 4; ++ct)
            #pragma unroll
            for (int r = 0; r < 4; ++r)
                out[(rowbase + kg * 4 + r) * 64 + ct * 16 + lr] = __float2half_rn(acc[ct][r]);
    }
}

// ---- pass B: scan block-bucket matrices -> per-(block,bucket) offsets + coarse bases ----
__global__ __launch_bounds__(256) void scanB_kernel(const int* __restrict__ histD, const int* __restrict__ histS,
                                                    int* __restrict__ offD, int* __restrict__ offS,
                                                    int* __restrict__ coarseD, int* __restrict__ coarseS) {
    __shared__ int totD[NB], totS[NB], baseD[NB + 1], baseS[NB + 1];
    int t = threadIdx.x;
    if (t < NB) { int s = 0; for (int k = 0; k < PB; k++) s += histD[k * NB + t]; totD[t] = s; }
    else if (t >= 128 && t < 128 + NB) { int j = t - 128; int s = 0; for (int k = 0; k < PB; k++) s += histS[k * NB + j]; totS[j] = s; }
    __syncthreads();
    if (t == 0)   { int r = 0; for (int j = 0; j < NB; j++) { baseD[j] = r; r += totD[j]; } baseD[NB] = r; }
    if (t == 128) { int r = 0; for (int j = 0; j < NB; j++) { baseS[j] = r; r += totS[j]; } baseS[NB] = r; }
    __syncthreads();
    if (t < NB) { int r = baseD[t]; for (int k = 0; k < PB; k++) { offD[k * NB + t] = r; r += histD[k * NB + t]; } }
    else if (t >= 128 && t < 128 + NB) { int j = t - 128; int r = baseS[j]; for (int k = 0; k < PB; k++) { offS[k * NB + j] = r; r += histS[k * NB + j]; } }
    if (t <= NB) coarseD[t] = baseD[t];
    if (t >= 128 && t <= 128 + NB) coarseS[t - 128] = baseS[t - 128];
}

// ---- pass C: partition edges into coarse buckets (LDS cursors, disjoint global slices) ----
__global__ __launch_bounds__(256) void partC_kernel(const int* __restrict__ src, const int* __restrict__ dst,
                                                    const float* __restrict__ ew,
                                                    const int* __restrict__ offD, const int* __restrict__ offS,
                                                    int2* __restrict__ partD, unsigned short* __restrict__ partS) {
    __shared__ int cD[NB], cS[NB];
    int tid = threadIdx.x;
    if (tid < NB) { cD[tid] = offD[blockIdx.x * NB + tid]; cS[tid] = offS[blockIdx.x * NB + tid]; }
    __syncthreads();
    int base = blockIdx.x * EPB;
    for (int i = tid; i < EPB; i += 256) {
        int s = src[base + i], d = dst[base + i];
        float w = ew[base + i];
        int p = atomicAdd(&cD[d >> 10], 1);              // LDS atomic
        partD[p] = make_int2(s | ((d & 1023) << 17), __float_as_int(w));
        int q = atomicAdd(&cS[s >> 10], 1);              // LDS atomic
        partS[q] = (unsigned short)(s & 1023);
    }
}

// ---- pass D2: per src-bucket fine histogram -> outdeg_inv ----
// v2: 2 blocks per bucket (r10 fineD pattern). Each block filter-counts its
// node-half (v>>9 == half) and writes its 512 outdeg_inv values.
__global__ __launch_bounds__(1024) void fineS_kernel(const unsigned short* __restrict__ partS, const int* __restrict__ coarseS,
                                                     float* __restrict__ outdeg_inv) {
    __shared__ int hist[512];
    int tid = threadIdx.x;
    const int bucket = blockIdx.x >> 1, half = blockIdx.x & 1;
    if (tid < 512) hist[tid] = 0;
    __syncthreads();
    int beg = coarseS[bucket], end = coarseS[bucket + 1];
    for (int i = beg + tid; i < end; i += 1024) {
        int v = partS[i];
        if ((v >> 9) == half) atomicAdd(&hist[v & 511], 1);
    }
    __syncthreads();
    if (tid < 512)
        outdeg_inv[bucket * 1024 + half * 512 + tid] = 1.0f / sqrtf((float)max(hist[tid], 1));
}

// ---- pass D: per dst-bucket fine sort -> row_off, indeg_inv, final CSR (weights pre-scaled) ----
// 2 blocks per bucket (r10-proven): both compute the full bucket hist+scan;
// each block scatters ONLY its node-half (d>>9 == half). Disjoint cursor halves.
__global__ __launch_bounds__(1024) void fineD_kernel(const int2* __restrict__ partD, const int* __restrict__ coarseD,
                                                     const float* __restrict__ outdeg_inv,
                                                     int2* __restrict__ edge_perm, int* __restrict__ row_off,
                                                     float* __restrict__ indeg_inv) {
    __shared__ int hist[1024], cursor[1024];
    __shared__ int wsum[16];
    int tid = threadIdx.x, lane = tid & 63, wid = tid >> 6;
    const int bucket = blockIdx.x >> 1, half = blockIdx.x & 1;
    hist[tid] = 0;
    __syncthreads();
    int beg = coarseD[bucket], end = coarseD[bucket + 1];
    for (int i = beg + tid; i < end; i += 1024) atomicAdd(&hist[(partD[i].x >> 17) & 1023], 1);
    __syncthreads();
    // exclusive scan of hist across the block (identical in both half-blocks)
    int v = hist[tid];
    int x = v;
    #pragma unroll
    for (int s = 1; s < 64; s <<= 1) { int t = __shfl_up(x, s, 64); if (lane >= s) x += t; }
    if (lane == 63) wsum[wid] = x;
    __syncthreads();
    if (wid == 0) {
        int ws = (lane < 16) ? wsum[lane] : 0;
        int y = ws;
        #pragma unroll
        for (int s = 1; s < 16; s <<= 1) { int t = __shfl_up(y, s, 64); if (lane >= s) y += t; }
        if (lane < 16) wsum[lane] = y - ws;
    }
    __syncthreads();
    int ex = wsum[wid] + x - v;                 // exclusive scan value for this node
    cursor[tid] = beg + ex;
    if (half == 0) {
        int node = bucket * 1024 + tid;
        row_off[node] = beg + ex;
        indeg_inv[node] = 1.0f / sqrtf((float)max(v, 1));
        if (bucket == NB - 1 && tid == 0) row_off[N_NODES] = N_EDGES;
    }
    __syncthreads();
    for (int i = beg + tid; i < end; i += 1024) {
        int2 t2 = partD[i];
        int d = (t2.x >> 17) & 1023;
        if ((d >> 9) == half) {                 // this block's node-half only
            int s = t2.x & 0x1FFFF;
            int p = atomicAdd(&cursor[d], 1);   // LDS atomic (disjoint halves across blocks)
            float w = __int_as_float(t2.y) * outdeg_inv[s];
            edge_perm[p] = make_int2(s, __float_as_int(w));
        }
    }
}

// ---------------- layer-0 aggregation (fp16 gather) + fused layer-1 transform ----------------
// pair processing (8 ep + 8 ht loads in flight) + fine-grained grid-stride (4096 blocks)
__global__ __launch_bounds__(256) void agg64_gemm_kernel(
    const __half* __restrict__ ht, const int* __restrict__ row_off,
    const int2* __restrict__ ep, const float* __restrict__ indeg_inv,
    const float* __restrict__ b0, const float* __restrict__ W1,
    __half* __restrict__ ht1, int N) {
    __shared__ float h1s[8][64];               // 2 node-slots per wave
    const int tid = threadIdx.x;
    const int lane = tid & 63;
    const int wv = tid >> 6;
    const int chunk = lane & 15;       // channels 4*chunk .. 4*chunk+3
    const int eslot = lane >> 4;       // 0..3
    const int hf = lane >> 5;          // gemv half
    const int c = lane & 31;           // gemv output column

    // per-lane invariants (W1 reads are L2-hot)
    float w1reg[32];
    #pragma unroll
    for (int j = 0; j < 32; ++j) w1reg[j] = W1[(hf * 32 + j) * 32 + c];
    const float bch = b0[(chunk << 2) | eslot];
    const char* htb = (const char*)ht;
    const unsigned coff = (unsigned)(chunk << 3);

    const int pair0 = (blockIdx.x * blockDim.x + tid) >> 6;
    const int npairs = N >> 1;
    const int nwaves = (gridDim.x * blockDim.x) >> 6;

    for (int pid = pair0; pid < npairs; pid += nwaves) {
        const int n0 = pid << 1;
        const int ro0 = row_off[n0], ro1 = row_off[n0 + 1], ro2 = row_off[n0 + 2];
        const int em0 = max(ro1 - 1, 0), em1 = max(ro2 - 1, 0);
        float4 a0 = {0, 0, 0, 0}, a1 = {0, 0, 0, 0};   // node0
        float4 c0 = {0, 0, 0, 0}, c1 = {0, 0, 0, 0};   // node1
        int e0 = ro0, e1 = ro1;
        while (true) {
            const int i00 = e0 + eslot, i01 = i00 + 4, i02 = i00 + 8, i03 = i00 + 12;
            const int j00 = e1 + eslot, j01 = j00 + 4, j02 = j00 + 8, j03 = j00 + 12;
            // 8 ep loads in flight
            int2 p00 = ep[min(i00, em0)];
            int2 p01 = ep[min(i01, em0)];
            int2 p02 = ep[min(i02, em0)];
            int2 p03 = ep[min(i03, em0)];
            int2 p10 = ep[min(j00, em1)];
            int2 p11 = ep[min(j01, em1)];
            int2 p12 = ep[min(j02, em1)];
            int2 p13 = ep[min(j03, em1)];
            float w00 = (i00 < ro1) ? __int_as_float(p00.y) : 0.0f;
            float w01 = (i01 < ro1) ? __int_as_float(p01.y) : 0.0f;
            float w02 = (i02 < ro1) ? __int_as_float(p02.y) : 0.0f;
            float w03 = (i03 < ro1) ? __int_as_float(p03.y) : 0.0f;
            float w10 = (j00 < ro2) ? __int_as_float(p10.y) : 0.0f;
            float w11 = (j01 < ro2) ? __int_as_float(p11.y) : 0.0f;
            float w12 = (j02 < ro2) ? __int_as_float(p12.y) : 0.0f;
            float w13 = (j03 < ro2) ? __int_as_float(p13.y) : 0.0f;
            // 8 gather loads in flight (8B each, 16 lanes/row -> 128B segments)
            H4 r00, r01, r02, r03, r10, r11, r12, r13;
            r00.i2 = *(const int2*)(htb + (((unsigned)p00.x << 7) | coff));
            r01.i2 = *(const int2*)(htb + (((unsigned)p01.x << 7) | coff));
            r02.i2 = *(const int2*)(htb + (((unsigned)p02.x << 7) | coff));
            r03.i2 = *(const int2*)(htb + (((unsigned)p03.x << 7) | coff));
            r10.i2 = *(const int2*)(htb + (((unsigned)p10.x << 7) | coff));
            r11.i2 = *(const int2*)(htb + (((unsigned)p11.x << 7) | coff));
            r12.i2 = *(const int2*)(htb + (((unsigned)p12.x << 7) | coff));
            r13.i2 = *(const int2*)(htb + (((unsigned)p13.x << 7) | coff));
            a0.x = fmaf(__half2float(r00.h[0]), w00, a0.x);
            a0.y = fmaf(__half2float(r00.h[1]), w00, a0.y);
            a0.z = fmaf(__half2float(r00.h[2]), w00, a0.z);
            a0.w = fmaf(__half2float(r00.h[3]), w00, a0.w);
            a1.x = fmaf(__half2float(r01.h[0]), w01, a1.x);
            a1.y = fmaf(__half2float(r01.h[1]), w01, a1.y);
            a1.z = fmaf(__half2float(r01.h[2]), w01, a1.z);
            a1.w = fmaf(__half2float(r01.h[3]), w01, a1.w);
            a0.x = fmaf(__half2float(r02.h[0]), w02, a0.x);
            a0.y = fmaf(__half2float(r02.h[1]), w02, a0.y);
            a0.z = fmaf(__half2float(r02.h[2]), w02, a0.z);
            a0.w = fmaf(__half2float(r02.h[3]), w02, a0.w);
            a1.x = fmaf(__half2float(r03.h[0]), w03, a1.x);
            a1.y = fmaf(__half2float(r03.h[1]), w03, a1.y);
            a1.z = fmaf(__half2float(r03.h[2]), w03, a1.z);
            a1.w = fmaf(__half2float(r03.h[3]), w03, a1.w);
            c0.x = fmaf(__half2float(r10.h[0]), w10, c0.x);
            c0.y = fmaf(__half2float(r10.h[1]), w10, c0.y);
            c0.z = fmaf(__half2float(r10.h[2]), w10, c0.z);
            c0.w = fmaf(__half2float(r10.h[3]), w10, c0.w);
            c1.x = fmaf(__half2float(r11.h[0]), w11, c1.x);
            c1.y = fmaf(__half2float(r11.h[1]), w11, c1.y);
            c1.z = fmaf(__half2float(r11.h[2]), w11, c1.z);
            c1.w = fmaf(__half2float(r11.h[3]), w11, c1.w);
            c0.x = fmaf(__half2float(r12.h[0]), w12, c0.x);
            c0.y = fmaf(__half2float(r12.h[1]), w12, c0.y);
            c0.z = fmaf(__half2float(r12.h[2]), w12, c0.z);
            c0.w = fmaf(__half2float(r12.h[3]), w12, c0.w);
            c1.x = fmaf(__half2float(r13.h[0]), w13, c1.x);
            c1.y = fmaf(__half2float(r13.h[1]), w13, c1.y);
            c1.z = fmaf(__half2float(r13.h[2]), w13, c1.z);
            c1.w = fmaf(__half2float(r13.h[3]), w13, c1.w);
            e0 += 16; e1 += 16;
            if (e0 >= ro1 && e1 >= ro2) break;
        }
        a0.x += a1.x; a0.y += a1.y; a0.z += a1.z; a0.w += a1.w;
        c0.x += c1.x; c0.y += c1.y; c0.z += c1.z; c0.w += c1.w;
        // butterfly-reduce across eslot (lane bits 4,5)
        #pragma unroll
        for (int s = 16; s <= 32; s <<= 1) {
            a0.x += __shfl_xor(a0.x, s, 64);
            a0.y += __shfl_xor(a0.y, s, 64);
            a0.z += __shfl_xor(a0.z, s, 64);
            a0.w += __shfl_xor(a0.w, s, 64);
            c0.x += __shfl_xor(c0.x, s, 64);
            c0.y += __shfl_xor(c0.y, s, 64);
            c0.z += __shfl_xor(c0.z, s, 64);
            c0.w += __shfl_xor(c0.w, s, 64);
        }
        // distributed tanh: lane (chunk,eslot) finishes channel 4*chunk+eslot for each node
        const float sc0 = indeg_inv[n0], sc1 = indeg_inv[n0 + 1];
        float v0 = (eslot == 0) ? a0.x : (eslot == 1) ? a0.y : (eslot == 2) ? a0.z : a0.w;
        float v1 = (eslot == 0) ? c0.x : (eslot == 1) ? c0.y : (eslot == 2) ? c0.z : c0.w;
        v0 = tanhf(fmaf(v0, sc0, bch));
        v1 = tanhf(fmaf(v1, sc1, bch));
        const int sl = wv << 1;
        h1s[sl][(chunk << 2) | eslot] = v0;
        h1s[sl + 1][(chunk << 2) | eslot] = v1;
        asm volatile("s_waitcnt lgkmcnt(0)" ::: "memory");
        // fused 64->32 gemv for both nodes: W1 column in registers
        float t0 = 0.0f, t1 = 0.0f;
        #pragma unroll
        for (int j4 = 0; j4 < 8; ++j4) {
            const float4 h0 = *(const float4*)&h1s[sl][hf * 32 + j4 * 4];       // broadcast
            const float4 h1 = *(const float4*)&h1s[sl + 1][hf * 32 + j4 * 4];   // broadcast
            t0 = fmaf(h0.x, w1reg[j4 * 4 + 0], t0);
            t0 = fmaf(h0.y, w1reg[j4 * 4 + 1], t0);
            t0 = fmaf(h0.z, w1reg[j4 * 4 + 2], t0);
            t0 = fmaf(h0.w, w1reg[j4 * 4 + 3], t0);
            t1 = fmaf(h1.x, w1reg[j4 * 4 + 0], t1);
            t1 = fmaf(h1.y, w1reg[j4 * 4 + 1], t1);
            t1 = fmaf(h1.z, w1reg[j4 * 4 + 2], t1);
            t1 = fmaf(h1.w, w1reg[j4 * 4 + 3], t1);
        }
        t0 += __shfl_xor(t0, 32, 64);
        t1 += __shfl_xor(t1, 32, 64);
        if (hf == 0) {
            ht1[(long)n0 * 32 + c] = __float2half_rn(t0);
            ht1[(long)(n0 + 1) * 32 + c] = __float2half_rn(t1);
        }
    }
}

// C=32 agg (fp16 gather) + fused K=32->1
// QUAD processing — 4 nodes per wave => 8 ep + 8 ht loads in flight.
__global__ __launch_bounds__(256) void agg32_dot_kernel(const __half* __restrict__ ht, const int* __restrict__ row_off,
                                 const int2* __restrict__ ep,
                                 const float* __restrict__ indeg_inv, const float* __restrict__ bias,
                                 const float* __restrict__ W2, float* __restrict__ ht2, int N) {
    int quad = (blockIdx.x * blockDim.x + threadIdx.x) >> 6;   // quad id
    int lane = threadIdx.x & 63;
    int n0 = quad << 2;
    if (n0 >= N) return;
    int chunk = lane & 7;        // channels 4*chunk .. 4*chunk+3
    int eslot = lane >> 3;       // 0..7
    int ro0 = row_off[n0], ro1 = row_off[n0 + 1], ro2 = row_off[n0 + 2];
    int ro3 = row_off[n0 + 3], ro4 = row_off[n0 + 4];
    int em0 = max(ro1 - 1, 0), em1 = max(ro2 - 1, 0);
    int em2 = max(ro3 - 1, 0), em3 = max(ro4 - 1, 0);
    const char* htb = (const char*)ht;
    unsigned coff = (unsigned)(chunk << 3);
    float4 a0 = {0, 0, 0, 0}, a1 = {0, 0, 0, 0};  // node0
    float4 b0 = {0, 0, 0, 0}, b1 = {0, 0, 0, 0};  // node1
    float4 c0 = {0, 0, 0, 0}, c1 = {0, 0, 0, 0};  // node2
    float4 d0 = {0, 0, 0, 0}, d1 = {0, 0, 0, 0};  // node3
    int e0 = ro0, e1 = ro1, e2 = ro2, e3 = ro3;
    while (e0 < ro1 || e1 < ro2 || e2 < ro3 || e3 < ro4) {
        int i00 = e0 + eslot, i01 = i00 + 8;
        int i10 = e1 + eslot, i11 = i10 + 8;
        int i20 = e2 + eslot, i21 = i20 + 8;
        int i30 = e3 + eslot, i31 = i30 + 8;
        // 8 ep loads in flight
        int2 p00 = ep[min(i00, em0)];
        int2 p01 = ep[min(i01, em0)];
        int2 p10 = ep[min(i10, em1)];
        int2 p11 = ep[min(i11, em1)];
        int2 p20 = ep[min(i20, em2)];
        int2 p21 = ep[min(i21, em2)];
        int2 p30 = ep[min(i30, em3)];
        int2 p31 = ep[min(i31, em3)];
        float w00 = (i00 < ro1) ? __int_as_float(p00.y) : 0.0f;
        float w01 = (i01 < ro1) ? __int_as_float(p01.y) : 0.0f;
        float w10 = (i10 < ro2) ? __int_as_float(p10.y) : 0.0f;
        float w11 = (i11 < ro2) ? __int_as_float(p11.y) : 0.0f;
        float w20 = (i20 < ro3) ? __int_as_float(p20.y) : 0.0f;
        float w21 = (i21 < ro3) ? __int_as_float(p21.y) : 0.0f;
        float w30 = (i30 < ro4) ? __int_as_float(p30.y) : 0.0f;
        float w31 = (i31 < ro4) ? __int_as_float(p31.y) : 0.0f;
        // 8 gather loads in flight (8B each, 8 lanes/row -> 64B rows)
        H4 r00, r01, r10, r11, r20, r21, r30, r31;
        r00.i2 = *(const int2*)(htb + (((unsigned)p00.x << 6) | coff));
        r01.i2 = *(const int2*)(htb + (((unsigned)p01.x << 6) | coff));
        r10.i2 = *(const int2*)(htb + (((unsigned)p10.x << 6) | coff));
        r11.i2 = *(const int2*)(htb + (((unsigned)p11.x << 6) | coff));
        r20.i2 = *(const int2*)(htb + (((unsigned)p20.x << 6) | coff));
        r21.i2 = *(const int2*)(htb + (((unsigned)p21.x << 6) | coff));
        r30.i2 = *(const int2*)(htb + (((unsigned)p30.x << 6) | coff));
        r31.i2 = *(const int2*)(htb + (((unsigned)p31.x << 6) | coff));
        a0.x = fmaf(__half2float(r00.h[0]), w00, a0.x);
        a0.y = fmaf(__half2float(r00.h[1]), w00, a0.y);
        a0.z = fmaf(__half2float(r00.h[2]), w00, a0.z);
        a0.w = fmaf(__half2float(r00.h[3]), w00, a0.w);
        a1.x = fmaf(__half2float(r01.h[0]), w01, a1.x);
        a1.y = fmaf(__half2float(r01.h[1]), w01, a1.y);
        a1.z = fmaf(__half2float(r01.h[2]), w01, a1.z);
        a1.w = fmaf(__half2float(r01.h[3]), w01, a1.w);
        b0.x = fmaf(__half2float(r10.h[0]), w10, b0.x);
        b0.y = fmaf(__half2float(r10.h[1]), w10, b0.y);
        b0.z = fmaf(__half2float(r10.h[2]), w10, b0.z);
        b0.w = fmaf(__half2float(r10.h[3]), w10, b0.w);
        b1.x = fmaf(__half2float(r11.h[0]), w11, b1.x);
        b1.y = fmaf(__half2float(r11.h[1]), w11, b1.y);
        b1.z = fmaf(__half2float(r11.h[2]), w11, b1.z);
        b1.w = fmaf(__half2float(r11.h[3]), w11, b1.w);
        c0.x = fmaf(__half2float(r20.h[0]), w20, c0.x);
        c0.y = fmaf(__half2float(r20.h[1]), w20, c0.y);
        c0.z = fmaf(__half2float(r20.h[2]), w20, c0.z);
        c0.w = fmaf(__half2float(r20.h[3]), w20, c0.w);
        c1.x = fmaf(__half2float(r21.h[0]), w21, c1.x);
        c1.y = fmaf(__half2float(r21.h[1]), w21, c1.y);
        c1.z = fmaf(__half2float(r21.h[2]), w21, c1.z);
        c1.w = fmaf(__half2float(r21.h[3]), w21, c1.w);
        d0.x = fmaf(__half2float(r30.h[0]), w30, d0.x);
        d0.y = fmaf(__half2float(r30.h[1]), w30, d0.y);
        d0.z = fmaf(__half2float(r30.h[2]), w30, d0.z);
        d0.w = fmaf(__half2float(r30.h[3]), w30, d0.w);
        d1.x = fmaf(__half2float(r31.h[0]), w31, d1.x);
        d1.y = fmaf(__half2float(r31.h[1]), w31, d1.y);
        d1.z = fmaf(__half2float(r31.h[2]), w31, d1.z);
        d1.w = fmaf(__half2float(r31.h[3]), w31, d1.w);
        e0 += 16; e1 += 16; e2 += 16; e3 += 16;
    }
    a0.x += a1.x; a0.y += a1.y; a0.z += a1.z; a0.w += a1.w;
    b0.x += b1.x; b0.y += b1.y; b0.z += b1.z; b0.w += b1.w;
    c0.x += c1.x; c0.y += c1.y; c0.z += c1.z; c0.w += c1.w;
    d0.x += d1.x; d0.y += d1.y; d0.z += d1.z; d0.w += d1.w;
    // butterfly-reduce across eslot (lane bits 3,4,5)
    #pragma unroll
    for (int s = 8; s <= 32; s <<= 1) {
        a0.x += __shfl_xor(a0.x, s, 64);
        a0.y += __shfl_xor(a0.y, s, 64);
        a0.z += __shfl_xor(a0.z, s, 64);
        a0.w += __shfl_xor(a0.w, s, 64);
        b0.x += __shfl_xor(b0.x, s, 64);
        b0.y += __shfl_xor(b0.y, s, 64);
        b0.z += __shfl_xor(b0.z, s, 64);
        b0.w += __shfl_xor(b0.w, s, 64);
        c0.x += __shfl_xor(c0.x, s, 64);
        c0.y += __shfl_xor(c0.y, s, 64);
        c0.z += __shfl_xor(c0.z, s, 64);
        c0.w += __shfl_xor(c0.w, s, 64);
        d0.x += __shfl_xor(d0.x, s, 64);
        d0.y += __shfl_xor(d0.y, s, 64);
        d0.z += __shfl_xor(d0.z, s, 64);
        d0.w += __shfl_xor(d0.w, s, 64);
    }
    // lane finishes channel ch = 4*chunk + (eslot&3); (eslot>=4 duplicates exactly)
    int q = eslot & 3;
    int ch = (chunk << 2) | q;
    float bb = bias[ch], ww = W2[ch];
    float s0 = indeg_inv[n0], s1 = indeg_inv[n0 + 1], s2 = indeg_inv[n0 + 2], s3 = indeg_inv[n0 + 3];
    float v0 = (q == 0) ? a0.x : (q == 1) ? a0.y : (q == 2) ? a0.z : a0.w;
    float v1 = (q == 0) ? b0.x : (q == 1) ? b0.y : (q == 2) ? b0.z : b0.w;
    float v2 = (q == 0) ? c0.x : (q == 1) ? c0.y : (q == 2) ? c0.z : c0.w;
    float v3 = (q == 0) ? d0.x : (q == 1) ? d0.y : (q == 2) ? d0.z : d0.w;
    float t0 = tanhf(fmaf(v0, s0, bb)) * ww;
    float t1 = tanhf(fmaf(v1, s1, bb)) * ww;
    float t2 = tanhf(fmaf(v2, s2, bb)) * ww;
    float t3 = tanhf(fmaf(v3, s3, bb)) * ww;
    // full-wave sum = 2 * sum_ch -> halve (exact: duplicates are bit-identical)
    #pragma unroll
    for (int s = 1; s <= 32; s <<= 1) {
        t0 += __shfl_xor(t0, s, 64);
        t1 += __shfl_xor(t1, s, 64);
        t2 += __shfl_xor(t2, s, 64);
        t3 += __shfl_xor(t3, s, 64);
    }
    if (lane == 0) {
        ht2[n0] = 0.5f * t0;
        ht2[n0 + 1] = 0.5f * t1;
        ht2[n0 + 2] = 0.5f * t2;
        ht2[n0 + 3] = 0.5f * t3;
    }
}

// C=1 final aggregation: 16 lanes per node (4 nodes/wave); coalesced edge reads
__global__ void agg1_kernel(const float* __restrict__ ht2, const int* __restrict__ row_off,
                            const int2* __restrict__ ep,
                            const float* __restrict__ indeg_inv, const float* __restrict__ bias,
                            float* __restrict__ out, int N) {
    int wave = (blockIdx.x * blockDim.x + threadIdx.x) >> 6;
    int lane = threadIdx.x & 63;
    int sub = lane >> 4;         // 0..3
    int slot = lane & 15;
    int node = wave * 4 + sub;
    if (node >= N) return;
    int beg = row_off[node], end = row_off[node + 1];
    float acc = 0.0f;
    for (int e = beg + slot; e < end; e += 16) {
        int2 t = ep[e];
        acc += ht2[t.x] * __int_as_float(t.y);
    }
    #pragma unroll
    for (int s = 1; s <= 8; s <<= 1) acc += __shfl_xor(acc, s, 64);  // within 16-lane group
    if (slot == 0) out[node] = acc * indeg_inv[node] + bias[0];
}

extern "C" void kernel_launch(void* const* d_in, const int* in_sizes, int n_in,
                              void* d_out, int out_size, void* d_ws, size_t ws_size,
                              hipStream_t stream) {
    const float* b_z = (const float*)d_in[0];
    const int*   src = (const int*)d_in[1];
    const int*   dst = (const int*)d_in[2];
    const float* ew  = (const float*)d_in[3];
    const float* W0 = (const float*)d_in[5];
    const float* b0 = (const float*)d_in[6];
    const float* W1 = (const float*)d_in[7];
    const float* b1 = (const float*)d_in[8];
    const float* W2 = (const float*)d_in[9];
    const float* b2 = (const float*)d_in[10];
    float* out = (float*)d_out;

    const int N = N_NODES;
    const int E = N_EDGES;

    // workspace layout (16B-aligned segments; ht de-aliased from partD so gemm can run first)
    char* p = (char*)d_ws;
    int*   row_off    = (int*)p;            p += (size_t)(N + 4) * 4;
    float* outdeg_inv = (float*)p;          p += (size_t)N * 4;
    float* indeg_inv  = (float*)p;          p += (size_t)N * 4;
    int*   histD      = (int*)p;            p += (size_t)PB * NB * 4;
    int*   histS      = (int*)p;            p += (size_t)PB * NB * 4;
    int*   offD       = (int*)p;            p += (size_t)PB * NB * 4;
    int*   offS       = (int*)p;            p += (size_t)PB * NB * 4;
    int*   coarseD    = (int*)p;            p += (size_t)(NB + 4) * 4;
    int*   coarseS    = (int*)p;            p += (size_t)(NB + 4) * 4;
    int2*  edge_perm  = (int2*)p;           p += (size_t)E * 8;
    char*  bufP       = p;                  p += (size_t)E * 8;      // partD / ht1
    char*  bufS       = p;                  p += (size_t)E * 2;      // partS / ht2
    char*  bufH       = p;                  /* N*64*2 = 13.1MB */    // ht (exclusive)
    // aliases with disjoint lifetimes:
    int2*           partD = (int2*)bufP;          // written partC, dead after fineD
    __half*         ht1   = (__half*)bufP;        // written agg64 (partD dead), read agg32
    unsigned short* partS = (unsigned short*)bufS;// written partC, dead after fineS
    float*          ht2   = (float*)bufS;         // written agg32 (partS dead), read agg1
    __half*         ht    = (__half*)bufH;        // written fusedA(gemm role), read agg64

    // ---- fused: coarse histograms (blocks 0..511) + MFMA layer-0 gemm (blocks 512..911) ----
    fusedA_kernel<<<PB + N / 256, 256, 0, stream>>>(src, dst, histD, histS, b_z, W0, ht);

    // ---- CSR build (two-level counting sort) ----
    scanB_kernel<<<1, 256, 0, stream>>>(histD, histS, offD, offS, coarseD, coarseS);
    partC_kernel<<<PB, 256, 0, stream>>>(src, dst, ew, offD, offS, partD, partS);
    fineS_kernel<<<NB * 2, 1024, 0, stream>>>(partS, coarseS, outdeg_inv);
    fineD_kernel<<<NB * 2, 1024, 0, stream>>>(partD, coarseD, outdeg_inv, edge_perm, row_off, indeg_inv);

    // ---- layer 0 aggregation + tanh + fused layer-1 transform (64 -> 32), fp16 out ----
    agg64_gemm_kernel<<<4096, 256, 0, stream>>>(ht, row_off, edge_perm, indeg_inv, b0, W1, ht1, N);

    // ---- layer 1 aggregation + tanh + fused layer-2 transform (32 -> 1) ----
    agg32_dot_kernel<<<N / 16, 256, 0, stream>>>(ht1, row_off, edge_perm, indeg_inv, b1, W2, ht2, N);

    // ---- layer 2 aggregation -> out ----
    agg1_kernel<<<N / 16, 256, 0, stream>>>(ht2, row_off, edge_perm, indeg_inv, b2, out, N);
}

// Round 12
// 311.468 us; speedup vs baseline: 1.0556x; 1.0556x over previous
//
#include <hip/hip_runtime.h>
#include <hip/hip_fp16.h>
#include <math.h>

#define N_NODES 102400
#define N_EDGES 1638400
#define NB 100            // coarse buckets: node range 1024 (102400/1024)
#define PB 256            // partition blocks (r10-proven; 512 regressed scanB's serial scan)
#define EPB (N_EDGES/PB)  // 6400 edges per partition block

union H4 { int2 i2; __half h[4]; };

typedef _Float16 f16;
typedef __attribute__((ext_vector_type(8))) _Float16 f16x8;
typedef __attribute__((ext_vector_type(4))) float f32x4;

// ---- fused pass A:
//   blocks 0..PB-1 : coarse dst/src histograms (LDS atomics)
//   blocks PB..    : layer-0 transform via MFMA (fp32->fp16 in-reg convert, fp32 accum)
__global__ __launch_bounds__(256) void fusedA_kernel(
    const int* __restrict__ src, const int* __restrict__ dst,
    int* __restrict__ histD, int* __restrict__ histS,
    const float* __restrict__ h, const float* __restrict__ W, __half* __restrict__ out) {
    const int tid = threadIdx.x;

    if (blockIdx.x < PB) {
        // ---------------- histogram role ----------------
        __shared__ int hD[NB], hS[NB];
        if (tid < NB) { hD[tid] = 0; hS[tid] = 0; }
        __syncthreads();
        int base = blockIdx.x * EPB;
        for (int i = tid; i < EPB; i += 256) {
            atomicAdd(&hD[dst[base + i] >> 10], 1);   // LDS atomic (CU-local)
            atomicAdd(&hS[src[base + i] >> 10], 1);
        }
        __syncthreads();
        if (tid < NB) {
            histD[blockIdx.x * NB + tid] = hD[tid];
            histS[blockIdx.x * NB + tid] = hS[tid];
        }
        return;
    }

    // ---------------- MFMA gemm role: out(fp16)[N][64] = h[N][128] @ W[128][64] ----------------
    const int lane = tid & 63;
    const int wid = tid >> 6;
    const int lr = lane & 15;        // A row / B col / D col (within 16x16 tile)
    const int kg = lane >> 4;        // k-group (0..3)
    const long bbase = (long)(blockIdx.x - PB) * 256 + wid * 16;

    f16x8 bf[4][4];
    #pragma unroll
    for (int ks = 0; ks < 4; ++ks)
        #pragma unroll
        for (int ct = 0; ct < 4; ++ct)
            #pragma unroll
            for (int j = 0; j < 8; ++j)
                bf[ks][ct][j] = (f16)W[(ks * 32 + kg * 8 + j) * 64 + ct * 16 + lr];

    #pragma unroll
    for (int t = 0; t < 4; ++t) {
        const long rowbase = bbase + t * 64;
        const float* hrow = h + (rowbase + lr) * 128 + kg * 8;
        f32x4 acc[4] = {{0,0,0,0},{0,0,0,0},{0,0,0,0},{0,0,0,0}};
        #pragma unroll
        for (int ks = 0; ks < 4; ++ks) {
            const float4 a0 = *(const float4*)(hrow + ks * 32);
            const float4 a1 = *(const float4*)(hrow + ks * 32 + 4);
            f16x8 af;
            af[0] = (f16)a0.x; af[1] = (f16)a0.y; af[2] = (f16)a0.z; af[3] = (f16)a0.w;
            af[4] = (f16)a1.x; af[5] = (f16)a1.y; af[6] = (f16)a1.z; af[7] = (f16)a1.w;
            #pragma unroll
            for (int ct = 0; ct < 4; ++ct)
                acc[ct] = __builtin_amdgcn_mfma_f32_16x16x32_f16(af, bf[ks][ct], acc[ct], 0, 0, 0);
        }
        #pragma unroll
        for (int ct = 0; ct < 4; ++ct)
            #pragma unroll
            for (int r = 0; r < 4; ++r)
                out[(rowbase + kg * 4 + r) * 64 + ct * 16 + lr] = __float2half_rn(acc[ct][r]);
    }
}

// ---- pass B: scan block-bucket matrices -> per-(block,bucket) offsets + coarse bases ----
__global__ __launch_bounds__(256) void scanB_kernel(const int* __restrict__ histD, const int* __restrict__ histS,
                                                    int* __restrict__ offD, int* __restrict__ offS,
                                                    int* __restrict__ coarseD, int* __restrict__ coarseS) {
    __shared__ int totD[NB], totS[NB], baseD[NB + 1], baseS[NB + 1];
    int t = threadIdx.x;
    if (t < NB) { int s = 0; for (int k = 0; k < PB; k++) s += histD[k * NB + t]; totD[t] = s; }
    else if (t >= 128 && t < 128 + NB) { int j = t - 128; int s = 0; for (int k = 0; k < PB; k++) s += histS[k * NB + j]; totS[j] = s; }
    __syncthreads();
    if (t == 0)   { int r = 0; for (int j = 0; j < NB; j++) { baseD[j] = r; r += totD[j]; } baseD[NB] = r; }
    if (t == 128) { int r = 0; for (int j = 0; j < NB; j++) { baseS[j] = r; r += totS[j]; } baseS[NB] = r; }
    __syncthreads();
    if (t < NB) { int r = baseD[t]; for (int k = 0; k < PB; k++) { offD[k * NB + t] = r; r += histD[k * NB + t]; } }
    else if (t >= 128 && t < 128 + NB) { int j = t - 128; int r = baseS[j]; for (int k = 0; k < PB; k++) { offS[k * NB + j] = r; r += histS[k * NB + j]; } }
    if (t <= NB) coarseD[t] = baseD[t];
    if (t >= 128 && t <= 128 + NB) coarseS[t - 128] = baseS[t - 128];
}

// ---- pass C: partition edges into coarse buckets (LDS cursors, disjoint global slices) ----
__global__ __launch_bounds__(256) void partC_kernel(const int* __restrict__ src, const int* __restrict__ dst,
                                                    const float* __restrict__ ew,
                                                    const int* __restrict__ offD, const int* __restrict__ offS,
                                                    int2* __restrict__ partD, unsigned short* __restrict__ partS) {
    __shared__ int cD[NB], cS[NB];
    int tid = threadIdx.x;
    if (tid < NB) { cD[tid] = offD[blockIdx.x * NB + tid]; cS[tid] = offS[blockIdx.x * NB + tid]; }
    __syncthreads();
    int base = blockIdx.x * EPB;
    for (int i = tid; i < EPB; i += 256) {
        int s = src[base + i], d = dst[base + i];
        float w = ew[base + i];
        int p = atomicAdd(&cD[d >> 10], 1);              // LDS atomic
        partD[p] = make_int2(s | ((d & 1023) << 17), __float_as_int(w));
        int q = atomicAdd(&cS[s >> 10], 1);              // LDS atomic
        partS[q] = (unsigned short)(s & 1023);
    }
}

// ---- pass D2: per src-bucket fine histogram -> outdeg_inv ----
// 2 blocks per bucket (r10 fineD pattern): each block filter-counts its
// node-half (v>>9 == half) and writes its 512 outdeg_inv values.
__global__ __launch_bounds__(1024) void fineS_kernel(const unsigned short* __restrict__ partS, const int* __restrict__ coarseS,
                                                     float* __restrict__ outdeg_inv) {
    __shared__ int hist[512];
    int tid = threadIdx.x;
    const int bucket = blockIdx.x >> 1, half = blockIdx.x & 1;
    if (tid < 512) hist[tid] = 0;
    __syncthreads();
    int beg = coarseS[bucket], end = coarseS[bucket + 1];
    for (int i = beg + tid; i < end; i += 1024) {
        int v = partS[i];
        if ((v >> 9) == half) atomicAdd(&hist[v & 511], 1);
    }
    __syncthreads();
    if (tid < 512)
        outdeg_inv[bucket * 1024 + half * 512 + tid] = 1.0f / sqrtf((float)max(hist[tid], 1));
}

// ---- pass D: per dst-bucket fine sort -> row_off, indeg_inv, final CSR (weights pre-scaled) ----
// 2 blocks per bucket (r10-proven): both compute the full bucket hist+scan;
// each block scatters ONLY its node-half (d>>9 == half). Disjoint cursor halves.
__global__ __launch_bounds__(1024) void fineD_kernel(const int2* __restrict__ partD, const int* __restrict__ coarseD,
                                                     const float* __restrict__ outdeg_inv,
                                                     int2* __restrict__ edge_perm, int* __restrict__ row_off,
                                                     float* __restrict__ indeg_inv) {
    __shared__ int hist[1024], cursor[1024];
    __shared__ int wsum[16];
    int tid = threadIdx.x, lane = tid & 63, wid = tid >> 6;
    const int bucket = blockIdx.x >> 1, half = blockIdx.x & 1;
    hist[tid] = 0;
    __syncthreads();
    int beg = coarseD[bucket], end = coarseD[bucket + 1];
    for (int i = beg + tid; i < end; i += 1024) atomicAdd(&hist[(partD[i].x >> 17) & 1023], 1);
    __syncthreads();
    // exclusive scan of hist across the block (identical in both half-blocks)
    int v = hist[tid];
    int x = v;
    #pragma unroll
    for (int s = 1; s < 64; s <<= 1) { int t = __shfl_up(x, s, 64); if (lane >= s) x += t; }
    if (lane == 63) wsum[wid] = x;
    __syncthreads();
    if (wid == 0) {
        int ws = (lane < 16) ? wsum[lane] : 0;
        int y = ws;
        #pragma unroll
        for (int s = 1; s < 16; s <<= 1) { int t = __shfl_up(y, s, 64); if (lane >= s) y += t; }
        if (lane < 16) wsum[lane] = y - ws;
    }
    __syncthreads();
    int ex = wsum[wid] + x - v;                 // exclusive scan value for this node
    cursor[tid] = beg + ex;
    if (half == 0) {
        int node = bucket * 1024 + tid;
        row_off[node] = beg + ex;
        indeg_inv[node] = 1.0f / sqrtf((float)max(v, 1));
        if (bucket == NB - 1 && tid == 0) row_off[N_NODES] = N_EDGES;
    }
    __syncthreads();
    for (int i = beg + tid; i < end; i += 1024) {
        int2 t2 = partD[i];
        int d = (t2.x >> 17) & 1023;
        if ((d >> 9) == half) {                 // this block's node-half only
            int s = t2.x & 0x1FFFF;
            int p = atomicAdd(&cursor[d], 1);   // LDS atomic (disjoint halves across blocks)
            float w = __int_as_float(t2.y) * outdeg_inv[s];
            edge_perm[p] = make_int2(s, __float_as_int(w));
        }
    }
}

// ---------------- layer-0 aggregation (fp16 gather) + fused layer-1 transform ----------------
// pair processing (8 ep + 8 ht loads in flight) + fine-grained grid-stride (4096 blocks)
__global__ __launch_bounds__(256) void agg64_gemm_kernel(
    const __half* __restrict__ ht, const int* __restrict__ row_off,
    const int2* __restrict__ ep, const float* __restrict__ indeg_inv,
    const float* __restrict__ b0, const float* __restrict__ W1,
    __half* __restrict__ ht1, int N) {
    __shared__ float h1s[8][64];               // 2 node-slots per wave
    const int tid = threadIdx.x;
    const int lane = tid & 63;
    const int wv = tid >> 6;
    const int chunk = lane & 15;       // channels 4*chunk .. 4*chunk+3
    const int eslot = lane >> 4;       // 0..3
    const int hf = lane >> 5;          // gemv half
    const int c = lane & 31;           // gemv output column

    // per-lane invariants (W1 reads are L2-hot)
    float w1reg[32];
    #pragma unroll
    for (int j = 0; j < 32; ++j) w1reg[j] = W1[(hf * 32 + j) * 32 + c];
    const float bch = b0[(chunk << 2) | eslot];
    const char* htb = (const char*)ht;
    const unsigned coff = (unsigned)(chunk << 3);

    const int pair0 = (blockIdx.x * blockDim.x + tid) >> 6;
    const int npairs = N >> 1;
    const int nwaves = (gridDim.x * blockDim.x) >> 6;

    for (int pid = pair0; pid < npairs; pid += nwaves) {
        const int n0 = pid << 1;
        const int ro0 = row_off[n0], ro1 = row_off[n0 + 1], ro2 = row_off[n0 + 2];
        const int em0 = max(ro1 - 1, 0), em1 = max(ro2 - 1, 0);
        float4 a0 = {0, 0, 0, 0}, a1 = {0, 0, 0, 0};   // node0
        float4 c0 = {0, 0, 0, 0}, c1 = {0, 0, 0, 0};   // node1
        int e0 = ro0, e1 = ro1;
        while (true) {
            const int i00 = e0 + eslot, i01 = i00 + 4, i02 = i00 + 8, i03 = i00 + 12;
            const int j00 = e1 + eslot, j01 = j00 + 4, j02 = j00 + 8, j03 = j00 + 12;
            // 8 ep loads in flight
            int2 p00 = ep[min(i00, em0)];
            int2 p01 = ep[min(i01, em0)];
            int2 p02 = ep[min(i02, em0)];
            int2 p03 = ep[min(i03, em0)];
            int2 p10 = ep[min(j00, em1)];
            int2 p11 = ep[min(j01, em1)];
            int2 p12 = ep[min(j02, em1)];
            int2 p13 = ep[min(j03, em1)];
            float w00 = (i00 < ro1) ? __int_as_float(p00.y) : 0.0f;
            float w01 = (i01 < ro1) ? __int_as_float(p01.y) : 0.0f;
            float w02 = (i02 < ro1) ? __int_as_float(p02.y) : 0.0f;
            float w03 = (i03 < ro1) ? __int_as_float(p03.y) : 0.0f;
            float w10 = (j00 < ro2) ? __int_as_float(p10.y) : 0.0f;
            float w11 = (j01 < ro2) ? __int_as_float(p11.y) : 0.0f;
            float w12 = (j02 < ro2) ? __int_as_float(p12.y) : 0.0f;
            float w13 = (j03 < ro2) ? __int_as_float(p13.y) : 0.0f;
            // 8 gather loads in flight (8B each, 16 lanes/row -> 128B segments)
            H4 r00, r01, r02, r03, r10, r11, r12, r13;
            r00.i2 = *(const int2*)(htb + (((unsigned)p00.x << 7) | coff));
            r01.i2 = *(const int2*)(htb + (((unsigned)p01.x << 7) | coff));
            r02.i2 = *(const int2*)(htb + (((unsigned)p02.x << 7) | coff));
            r03.i2 = *(const int2*)(htb + (((unsigned)p03.x << 7) | coff));
            r10.i2 = *(const int2*)(htb + (((unsigned)p10.x << 7) | coff));
            r11.i2 = *(const int2*)(htb + (((unsigned)p11.x << 7) | coff));
            r12.i2 = *(const int2*)(htb + (((unsigned)p12.x << 7) | coff));
            r13.i2 = *(const int2*)(htb + (((unsigned)p13.x << 7) | coff));
            a0.x = fmaf(__half2float(r00.h[0]), w00, a0.x);
            a0.y = fmaf(__half2float(r00.h[1]), w00, a0.y);
            a0.z = fmaf(__half2float(r00.h[2]), w00, a0.z);
            a0.w = fmaf(__half2float(r00.h[3]), w00, a0.w);
            a1.x = fmaf(__half2float(r01.h[0]), w01, a1.x);
            a1.y = fmaf(__half2float(r01.h[1]), w01, a1.y);
            a1.z = fmaf(__half2float(r01.h[2]), w01, a1.z);
            a1.w = fmaf(__half2float(r01.h[3]), w01, a1.w);
            a0.x = fmaf(__half2float(r02.h[0]), w02, a0.x);
            a0.y = fmaf(__half2float(r02.h[1]), w02, a0.y);
            a0.z = fmaf(__half2float(r02.h[2]), w02, a0.z);
            a0.w = fmaf(__half2float(r02.h[3]), w02, a0.w);
            a1.x = fmaf(__half2float(r03.h[0]), w03, a1.x);
            a1.y = fmaf(__half2float(r03.h[1]), w03, a1.y);
            a1.z = fmaf(__half2float(r03.h[2]), w03, a1.z);
            a1.w = fmaf(__half2float(r03.h[3]), w03, a1.w);
            c0.x = fmaf(__half2float(r10.h[0]), w10, c0.x);
            c0.y = fmaf(__half2float(r10.h[1]), w10, c0.y);
            c0.z = fmaf(__half2float(r10.h[2]), w10, c0.z);
            c0.w = fmaf(__half2float(r10.h[3]), w10, c0.w);
            c1.x = fmaf(__half2float(r11.h[0]), w11, c1.x);
            c1.y = fmaf(__half2float(r11.h[1]), w11, c1.y);
            c1.z = fmaf(__half2float(r11.h[2]), w11, c1.z);
            c1.w = fmaf(__half2float(r11.h[3]), w11, c1.w);
            c0.x = fmaf(__half2float(r12.h[0]), w12, c0.x);
            c0.y = fmaf(__half2float(r12.h[1]), w12, c0.y);
            c0.z = fmaf(__half2float(r12.h[2]), w12, c0.z);
            c0.w = fmaf(__half2float(r12.h[3]), w12, c0.w);
            c1.x = fmaf(__half2float(r13.h[0]), w13, c1.x);
            c1.y = fmaf(__half2float(r13.h[1]), w13, c1.y);
            c1.z = fmaf(__half2float(r13.h[2]), w13, c1.z);
            c1.w = fmaf(__half2float(r13.h[3]), w13, c1.w);
            e0 += 16; e1 += 16;
            if (e0 >= ro1 && e1 >= ro2) break;
        }
        a0.x += a1.x; a0.y += a1.y; a0.z += a1.z; a0.w += a1.w;
        c0.x += c1.x; c0.y += c1.y; c0.z += c1.z; c0.w += c1.w;
        // butterfly-reduce across eslot (lane bits 4,5)
        #pragma unroll
        for (int s = 16; s <= 32; s <<= 1) {
            a0.x += __shfl_xor(a0.x, s, 64);
            a0.y += __shfl_xor(a0.y, s, 64);
            a0.z += __shfl_xor(a0.z, s, 64);
            a0.w += __shfl_xor(a0.w, s, 64);
            c0.x += __shfl_xor(c0.x, s, 64);
            c0.y += __shfl_xor(c0.y, s, 64);
            c0.z += __shfl_xor(c0.z, s, 64);
            c0.w += __shfl_xor(c0.w, s, 64);
        }
        // distributed tanh: lane (chunk,eslot) finishes channel 4*chunk+eslot for each node
        const float sc0 = indeg_inv[n0], sc1 = indeg_inv[n0 + 1];
        float v0 = (eslot == 0) ? a0.x : (eslot == 1) ? a0.y : (eslot == 2) ? a0.z : a0.w;
        float v1 = (eslot == 0) ? c0.x : (eslot == 1) ? c0.y : (eslot == 2) ? c0.z : c0.w;
        v0 = tanhf(fmaf(v0, sc0, bch));
        v1 = tanhf(fmaf(v1, sc1, bch));
        const int sl = wv << 1;
        h1s[sl][(chunk << 2) | eslot] = v0;
        h1s[sl + 1][(chunk << 2) | eslot] = v1;
        asm volatile("s_waitcnt lgkmcnt(0)" ::: "memory");
        // fused 64->32 gemv for both nodes: W1 column in registers
        float t0 = 0.0f, t1 = 0.0f;
        #pragma unroll
        for (int j4 = 0; j4 < 8; ++j4) {
            const float4 h0 = *(const float4*)&h1s[sl][hf * 32 + j4 * 4];       // broadcast
            const float4 h1 = *(const float4*)&h1s[sl + 1][hf * 32 + j4 * 4];   // broadcast
            t0 = fmaf(h0.x, w1reg[j4 * 4 + 0], t0);
            t0 = fmaf(h0.y, w1reg[j4 * 4 + 1], t0);
            t0 = fmaf(h0.z, w1reg[j4 * 4 + 2], t0);
            t0 = fmaf(h0.w, w1reg[j4 * 4 + 3], t0);
            t1 = fmaf(h1.x, w1reg[j4 * 4 + 0], t1);
            t1 = fmaf(h1.y, w1reg[j4 * 4 + 1], t1);
            t1 = fmaf(h1.z, w1reg[j4 * 4 + 2], t1);
            t1 = fmaf(h1.w, w1reg[j4 * 4 + 3], t1);
        }
        t0 += __shfl_xor(t0, 32, 64);
        t1 += __shfl_xor(t1, 32, 64);
        if (hf == 0) {
            ht1[(long)n0 * 32 + c] = __float2half_rn(t0);
            ht1[(long)(n0 + 1) * 32 + c] = __float2half_rn(t1);
        }
    }
}

// C=32 agg (fp16 gather) + fused K=32->1
// QUAD processing — 4 nodes per wave => 8 ep + 8 ht loads in flight.
__global__ __launch_bounds__(256) void agg32_dot_kernel(const __half* __restrict__ ht, const int* __restrict__ row_off,
                                 const int2* __restrict__ ep,
                                 const float* __restrict__ indeg_inv, const float* __restrict__ bias,
                                 const float* __restrict__ W2, float* __restrict__ ht2, int N) {
    int quad = (blockIdx.x * blockDim.x + threadIdx.x) >> 6;   // quad id
    int lane = threadIdx.x & 63;
    int n0 = quad << 2;
    if (n0 >= N) return;
    int chunk = lane & 7;        // channels 4*chunk .. 4*chunk+3
    int eslot = lane >> 3;       // 0..7
    int ro0 = row_off[n0], ro1 = row_off[n0 + 1], ro2 = row_off[n0 + 2];
    int ro3 = row_off[n0 + 3], ro4 = row_off[n0 + 4];
    int em0 = max(ro1 - 1, 0), em1 = max(ro2 - 1, 0);
    int em2 = max(ro3 - 1, 0), em3 = max(ro4 - 1, 0);
    const char* htb = (const char*)ht;
    unsigned coff = (unsigned)(chunk << 3);
    float4 a0 = {0, 0, 0, 0}, a1 = {0, 0, 0, 0};  // node0
    float4 b0 = {0, 0, 0, 0}, b1 = {0, 0, 0, 0};  // node1
    float4 c0 = {0, 0, 0, 0}, c1 = {0, 0, 0, 0};  // node2
    float4 d0 = {0, 0, 0, 0}, d1 = {0, 0, 0, 0};  // node3
    int e0 = ro0, e1 = ro1, e2 = ro2, e3 = ro3;
    while (e0 < ro1 || e1 < ro2 || e2 < ro3 || e3 < ro4) {
        int i00 = e0 + eslot, i01 = i00 + 8;
        int i10 = e1 + eslot, i11 = i10 + 8;
        int i20 = e2 + eslot, i21 = i20 + 8;
        int i30 = e3 + eslot, i31 = i30 + 8;
        // 8 ep loads in flight
        int2 p00 = ep[min(i00, em0)];
        int2 p01 = ep[min(i01, em0)];
        int2 p10 = ep[min(i10, em1)];
        int2 p11 = ep[min(i11, em1)];
        int2 p20 = ep[min(i20, em2)];
        int2 p21 = ep[min(i21, em2)];
        int2 p30 = ep[min(i30, em3)];
        int2 p31 = ep[min(i31, em3)];
        float w00 = (i00 < ro1) ? __int_as_float(p00.y) : 0.0f;
        float w01 = (i01 < ro1) ? __int_as_float(p01.y) : 0.0f;
        float w10 = (i10 < ro2) ? __int_as_float(p10.y) : 0.0f;
        float w11 = (i11 < ro2) ? __int_as_float(p11.y) : 0.0f;
        float w20 = (i20 < ro3) ? __int_as_float(p20.y) : 0.0f;
        float w21 = (i21 < ro3) ? __int_as_float(p21.y) : 0.0f;
        float w30 = (i30 < ro4) ? __int_as_float(p30.y) : 0.0f;
        float w31 = (i31 < ro4) ? __int_as_float(p31.y) : 0.0f;
        // 8 gather loads in flight (8B each, 8 lanes/row -> 64B rows)
        H4 r00, r01, r10, r11, r20, r21, r30, r31;
        r00.i2 = *(const int2*)(htb + (((unsigned)p00.x << 6) | coff));
        r01.i2 = *(const int2*)(htb + (((unsigned)p01.x << 6) | coff));
        r10.i2 = *(const int2*)(htb + (((unsigned)p10.x << 6) | coff));
        r11.i2 = *(const int2*)(htb + (((unsigned)p11.x << 6) | coff));
        r20.i2 = *(const int2*)(htb + (((unsigned)p20.x << 6) | coff));
        r21.i2 = *(const int2*)(htb + (((unsigned)p21.x << 6) | coff));
        r30.i2 = *(const int2*)(htb + (((unsigned)p30.x << 6) | coff));
        r31.i2 = *(const int2*)(htb + (((unsigned)p31.x << 6) | coff));
        a0.x = fmaf(__half2float(r00.h[0]), w00, a0.x);
        a0.y = fmaf(__half2float(r00.h[1]), w00, a0.y);
        a0.z = fmaf(__half2float(r00.h[2]), w00, a0.z);
        a0.w = fmaf(__half2float(r00.h[3]), w00, a0.w);
        a1.x = fmaf(__half2float(r01.h[0]), w01, a1.x);
        a1.y = fmaf(__half2float(r01.h[1]), w01, a1.y);
        a1.z = fmaf(__half2float(r01.h[2]), w01, a1.z);
        a1.w = fmaf(__half2float(r01.h[3]), w01, a1.w);
        b0.x = fmaf(__half2float(r10.h[0]), w10, b0.x);
        b0.y = fmaf(__half2float(r10.h[1]), w10, b0.y);
        b0.z = fmaf(__half2float(r10.h[2]), w10, b0.z);
        b0.w = fmaf(__half2float(r10.h[3]), w10, b0.w);
        b1.x = fmaf(__half2float(r11.h[0]), w11, b1.x);
        b1.y = fmaf(__half2float(r11.h[1]), w11, b1.y);
        b1.z = fmaf(__half2float(r11.h[2]), w11, b1.z);
        b1.w = fmaf(__half2float(r11.h[3]), w11, b1.w);
        c0.x = fmaf(__half2float(r20.h[0]), w20, c0.x);
        c0.y = fmaf(__half2float(r20.h[1]), w20, c0.y);
        c0.z = fmaf(__half2float(r20.h[2]), w20, c0.z);
        c0.w = fmaf(__half2float(r20.h[3]), w20, c0.w);
        c1.x = fmaf(__half2float(r21.h[0]), w21, c1.x);
        c1.y = fmaf(__half2float(r21.h[1]), w21, c1.y);
        c1.z = fmaf(__half2float(r21.h[2]), w21, c1.z);
        c1.w = fmaf(__half2float(r21.h[3]), w21, c1.w);
        d0.x = fmaf(__half2float(r30.h[0]), w30, d0.x);
        d0.y = fmaf(__half2float(r30.h[1]), w30, d0.y);
        d0.z = fmaf(__half2float(r30.h[2]), w30, d0.z);
        d0.w = fmaf(__half2float(r30.h[3]), w30, d0.w);
        d1.x = fmaf(__half2float(r31.h[0]), w31, d1.x);
        d1.y = fmaf(__half2float(r31.h[1]), w31, d1.y);
        d1.z = fmaf(__half2float(r31.h[2]), w31, d1.z);
        d1.w = fmaf(__half2float(r31.h[3]), w31, d1.w);
        e0 += 16; e1 += 16; e2 += 16; e3 += 16;
    }
    a0.x += a1.x; a0.y += a1.y; a0.z += a1.z; a0.w += a1.w;
    b0.x += b1.x; b0.y += b1.y; b0.z += b1.z; b0.w += b1.w;
    c0.x += c1.x; c0.y += c1.y; c0.z += c1.z; c0.w += c1.w;
    d0.x += d1.x; d0.y += d1.y; d0.z += d1.z; d0.w += d1.w;
    // butterfly-reduce across eslot (lane bits 3,4,5)
    #pragma unroll
    for (int s = 8; s <= 32; s <<= 1) {
        a0.x += __shfl_xor(a0.x, s, 64);
        a0.y += __shfl_xor(a0.y, s, 64);
        a0.z += __shfl_xor(a0.z, s, 64);
        a0.w += __shfl_xor(a0.w, s, 64);
        b0.x += __shfl_xor(b0.x, s, 64);
        b0.y += __shfl_xor(b0.y, s, 64);
        b0.z += __shfl_xor(b0.z, s, 64);
        b0.w += __shfl_xor(b0.w, s, 64);
        c0.x += __shfl_xor(c0.x, s, 64);
        c0.y += __shfl_xor(c0.y, s, 64);
        c0.z += __shfl_xor(c0.z, s, 64);
        c0.w += __shfl_xor(c0.w, s, 64);
        d0.x += __shfl_xor(d0.x, s, 64);
        d0.y += __shfl_xor(d0.y, s, 64);
        d0.z += __shfl_xor(d0.z, s, 64);
        d0.w += __shfl_xor(d0.w, s, 64);
    }
    // lane finishes channel ch = 4*chunk + (eslot&3); (eslot>=4 duplicates exactly)
    int q = eslot & 3;
    int ch = (chunk << 2) | q;
    float bb = bias[ch], ww = W2[ch];
    float s0 = indeg_inv[n0], s1 = indeg_inv[n0 + 1], s2 = indeg_inv[n0 + 2], s3 = indeg_inv[n0 + 3];
    float v0 = (q == 0) ? a0.x : (q == 1) ? a0.y : (q == 2) ? a0.z : a0.w;
    float v1 = (q == 0) ? b0.x : (q == 1) ? b0.y : (q == 2) ? b0.z : b0.w;
    float v2 = (q == 0) ? c0.x : (q == 1) ? c0.y : (q == 2) ? c0.z : c0.w;
    float v3 = (q == 0) ? d0.x : (q == 1) ? d0.y : (q == 2) ? d0.z : d0.w;
    float t0 = tanhf(fmaf(v0, s0, bb)) * ww;
    float t1 = tanhf(fmaf(v1, s1, bb)) * ww;
    float t2 = tanhf(fmaf(v2, s2, bb)) * ww;
    float t3 = tanhf(fmaf(v3, s3, bb)) * ww;
    // full-wave sum = 2 * sum_ch -> halve (exact: duplicates are bit-identical)
    #pragma unroll
    for (int s = 1; s <= 32; s <<= 1) {
        t0 += __shfl_xor(t0, s, 64);
        t1 += __shfl_xor(t1, s, 64);
        t2 += __shfl_xor(t2, s, 64);
        t3 += __shfl_xor(t3, s, 64);
    }
    if (lane == 0) {
        ht2[n0] = 0.5f * t0;
        ht2[n0 + 1] = 0.5f * t1;
        ht2[n0 + 2] = 0.5f * t2;
        ht2[n0 + 3] = 0.5f * t3;
    }
}

// C=1 final aggregation: 16 lanes per node (4 nodes/wave); coalesced edge reads
__global__ void agg1_kernel(const float* __restrict__ ht2, const int* __restrict__ row_off,
                            const int2* __restrict__ ep,
                            const float* __restrict__ indeg_inv, const float* __restrict__ bias,
                            float* __restrict__ out, int N) {
    int wave = (blockIdx.x * blockDim.x + threadIdx.x) >> 6;
    int lane = threadIdx.x & 63;
    int sub = lane >> 4;         // 0..3
    int slot = lane & 15;
    int node = wave * 4 + sub;
    if (node >= N) return;
    int beg = row_off[node], end = row_off[node + 1];
    float acc = 0.0f;
    for (int e = beg + slot; e < end; e += 16) {
        int2 t = ep[e];
        acc += ht2[t.x] * __int_as_float(t.y);
    }
    #pragma unroll
    for (int s = 1; s <= 8; s <<= 1) acc += __shfl_xor(acc, s, 64);  // within 16-lane group
    if (slot == 0) out[node] = acc * indeg_inv[node] + bias[0];
}

extern "C" void kernel_launch(void* const* d_in, const int* in_sizes, int n_in,
                              void* d_out, int out_size, void* d_ws, size_t ws_size,
                              hipStream_t stream) {
    const float* b_z = (const float*)d_in[0];
    const int*   src = (const int*)d_in[1];
    const int*   dst = (const int*)d_in[2];
    const float* ew  = (const float*)d_in[3];
    const float* W0 = (const float*)d_in[5];
    const float* b0 = (const float*)d_in[6];
    const float* W1 = (const float*)d_in[7];
    const float* b1 = (const float*)d_in[8];
    const float* W2 = (const float*)d_in[9];
    const float* b2 = (const float*)d_in[10];
    float* out = (float*)d_out;

    const int N = N_NODES;
    const int E = N_EDGES;

    // workspace layout (16B-aligned segments; ht de-aliased from partD so gemm can run first)
    char* p = (char*)d_ws;
    int*   row_off    = (int*)p;            p += (size_t)(N + 4) * 4;
    float* outdeg_inv = (float*)p;          p += (size_t)N * 4;
    float* indeg_inv  = (float*)p;          p += (size_t)N * 4;
    int*   histD      = (int*)p;            p += (size_t)PB * NB * 4;
    int*   histS      = (int*)p;            p += (size_t)PB * NB * 4;
    int*   offD       = (int*)p;            p += (size_t)PB * NB * 4;
    int*   offS       = (int*)p;            p += (size_t)PB * NB * 4;
    int*   coarseD    = (int*)p;            p += (size_t)(NB + 4) * 4;
    int*   coarseS    = (int*)p;            p += (size_t)(NB + 4) * 4;
    int2*  edge_perm  = (int2*)p;           p += (size_t)E * 8;
    char*  bufP       = p;                  p += (size_t)E * 8;      // partD / ht1
    char*  bufS       = p;                  p += (size_t)E * 2;      // partS / ht2
    char*  bufH       = p;                  /* N*64*2 = 13.1MB */    // ht (exclusive)
    // aliases with disjoint lifetimes:
    int2*           partD = (int2*)bufP;          // written partC, dead after fineD
    __half*         ht1   = (__half*)bufP;        // written agg64 (partD dead), read agg32
    unsigned short* partS = (unsigned short*)bufS;// written partC, dead after fineS
    float*          ht2   = (float*)bufS;         // written agg32 (partS dead), read agg1
    __half*         ht    = (__half*)bufH;        // written fusedA(gemm role), read agg64

    // ---- fused: coarse histograms (blocks 0..255) + MFMA layer-0 gemm (blocks 256..655) ----
    fusedA_kernel<<<PB + N / 256, 256, 0, stream>>>(src, dst, histD, histS, b_z, W0, ht);

    // ---- CSR build (two-level counting sort) ----
    scanB_kernel<<<1, 256, 0, stream>>>(histD, histS, offD, offS, coarseD, coarseS);
    partC_kernel<<<PB, 256, 0, stream>>>(src, dst, ew, offD, offS, partD, partS);
    fineS_kernel<<<NB * 2, 1024, 0, stream>>>(partS, coarseS, outdeg_inv);
    fineD_kernel<<<NB * 2, 1024, 0, stream>>>(partD, coarseD, outdeg_inv, edge_perm, row_off, indeg_inv);

    // ---- layer 0 aggregation + tanh + fused layer-1 transform (64 -> 32), fp16 out ----
    agg64_gemm_kernel<<<4096, 256, 0, stream>>>(ht, row_off, edge_perm, indeg_inv, b0, W1, ht1, N);

    // ---- layer 1 aggregation + tanh + fused layer-2 transform (32 -> 1) ----
    agg32_dot_kernel<<<N / 16, 256, 0, stream>>>(ht1, row_off, edge_perm, indeg_inv, b1, W2, ht2, N);

    // ---- layer 2 aggregation -> out ----
    agg1_kernel<<<N / 16, 256, 0, stream>>>(ht2, row_off, edge_perm, indeg_inv, b2, out, N);
}